// Round 1
// baseline (697.052 us; speedup 1.0000x reference)
//
#include <hip/hip_runtime.h>
#include <math.h>

#define NH    8
#define CPH   48
#define D     384
#define QC    1152
#define HF    192
#define WFULL 192
#define HP    96
#define WP    96
#define NP    9216    // 96*96
#define NF    36864   // 192*192

__device__ __forceinline__ void fma4(float4& a, float s, const float4& v) {
    a.x += s * v.x; a.y += s * v.y; a.z += s * v.z; a.w += s * v.w;
}
__device__ __forceinline__ float gelu_exact(float v) {
    return 0.5f * v * (1.f + erff(v * 0.70710678118654752440f));
}

__global__ void k_zero(float* p, int n) {
    int i = blockIdx.x * 256 + threadIdx.x;
    if (i < n) p[i] = 0.f;
}

// ---------------- K1: qkv 1x1 conv fused with 2x2 maxpool --------------------
// tile: 128 out-channels x (2 rows x 64 cols full-res) -> 128 x 32 pooled
// thread: 8 och x (2x4 full-res px -> 2 pooled px)
__global__ __launch_bounds__(256) void k_qkv_pool(
    const float* __restrict__ x, const float* __restrict__ wq,
    const float* __restrict__ bq, float* __restrict__ pooled) {
    __shared__ float Xs[32][2][64];   // [k][row][col]
    __shared__ float Ws[32][132];     // [k][och], padded pitch (16B-aligned)
    int tid = threadIdx.x;
    int tx = tid & 15, ty = tid >> 4;
    int o0  = blockIdx.z * 128;
    int ph  = blockIdx.y;
    int pw0 = blockIdx.x * 32;
    int r0  = 2 * ph;
    int c0  = blockIdx.x * 64;

    float4 acc0[8], acc1[8];
#pragma unroll
    for (int i = 0; i < 8; i++) {
        acc0[i] = make_float4(0.f, 0.f, 0.f, 0.f);
        acc1[i] = make_float4(0.f, 0.f, 0.f, 0.f);
    }
    for (int kc = 0; kc < D; kc += 32) {
        __syncthreads();
#pragma unroll
        for (int it = 0; it < 16; it++) {       // X tile: 32k x 2r x 64c
            int li = tid + 256 * it;
            int col = li & 63, r = (li >> 6) & 1, k = li >> 7;
            Xs[k][r][col] = x[(size_t)(kc + k) * NF + (size_t)(r0 + r) * WFULL + c0 + col];
        }
#pragma unroll
        for (int it = 0; it < 16; it++) {       // W tile: 128o x 32k (transposed)
            int li = tid + 256 * it;
            int kk = li & 31, ol = li >> 5;
            Ws[kk][ol] = wq[(size_t)(o0 + ol) * D + kc + kk];
        }
        __syncthreads();
#pragma unroll
        for (int k = 0; k < 32; k++) {
            float4 xv0 = *(const float4*)&Xs[k][0][tx * 4];
            float4 xv1 = *(const float4*)&Xs[k][1][tx * 4];
            float4 wa  = *(const float4*)&Ws[k][ty * 8];
            float4 wb  = *(const float4*)&Ws[k][ty * 8 + 4];
            fma4(acc0[0], wa.x, xv0); fma4(acc1[0], wa.x, xv1);
            fma4(acc0[1], wa.y, xv0); fma4(acc1[1], wa.y, xv1);
            fma4(acc0[2], wa.z, xv0); fma4(acc1[2], wa.z, xv1);
            fma4(acc0[3], wa.w, xv0); fma4(acc1[3], wa.w, xv1);
            fma4(acc0[4], wb.x, xv0); fma4(acc1[4], wb.x, xv1);
            fma4(acc0[5], wb.y, xv0); fma4(acc1[5], wb.y, xv1);
            fma4(acc0[6], wb.z, xv0); fma4(acc1[6], wb.z, xv1);
            fma4(acc0[7], wb.w, xv0); fma4(acc1[7], wb.w, xv1);
        }
    }
#pragma unroll
    for (int i = 0; i < 8; i++) {
        int o = o0 + ty * 8 + i;
        float b = bq[o];
        float v0 = fmaxf(fmaxf(acc0[i].x, acc0[i].y), fmaxf(acc1[i].x, acc1[i].y)) + b;
        float v1 = fmaxf(fmaxf(acc0[i].z, acc0[i].w), fmaxf(acc1[i].z, acc1[i].w)) + b;
        float2 vv = make_float2(v0, v1);
        *(float2*)&pooled[(size_t)o * NP + ph * WP + pw0 + tx * 2] = vv;
    }
}

// ---------------- K2: depthwise 3x3 conv, SAME padding -----------------------
__global__ __launch_bounds__(256) void k_dwconv(
    const float* __restrict__ pooled, const float* __restrict__ wd,
    const float* __restrict__ bd, float* __restrict__ out) {
    int gid = blockIdx.x * 256 + threadIdx.x;
    int ch = gid / NP;
    int n  = gid - ch * NP;
    int y  = n / WP;
    int x0 = n - y * WP;
    const float* src = pooled + (size_t)ch * NP;
    const float* w = wd + ch * 9;
    float s = bd[ch];
#pragma unroll
    for (int dy = 0; dy < 3; dy++) {
        int yy = y + dy - 1;
        if (yy < 0 || yy >= HP) continue;
#pragma unroll
        for (int dx = 0; dx < 3; dx++) {
            int xx = x0 + dx - 1;
            if (xx < 0 || xx >= WP) continue;
            s += src[yy * WP + xx] * w[dy * 3 + dx];
        }
    }
    out[gid] = s;
}

// ---------------- K3: attn partials S = q.k^T, plus sq-norms -----------------
// grid (96 chunks, 8 heads), 64 threads; chunk = 96 spatial elements
__global__ __launch_bounds__(64) void k_attn(
    const float* __restrict__ qkv, float* __restrict__ S,
    float* __restrict__ qn, float* __restrict__ kn) {
    __shared__ float qs[48][97], ks[48][97];
    int t = threadIdx.x;
    int head = blockIdx.y;
    int n0 = blockIdx.x * 96;
    const float* qb = qkv + (size_t)(head * CPH) * NP + n0;
    const float* kb = qkv + (size_t)(D + head * CPH) * NP + n0;
    for (int it = 0; it < 72; it++) {
        int li = t + 64 * it;
        int col = li % 96, row = li / 96;
        qs[row][col] = qb[(size_t)row * NP + col];
        ks[row][col] = kb[(size_t)row * NP + col];
    }
    __syncthreads();
    int tr = t >> 3, tc = t & 7;        // 8x8 threads, 6x6 pairs each
    float acc[6][6] = {};
    for (int n = 0; n < 96; n++) {
        float qv[6], kv[6];
#pragma unroll
        for (int i = 0; i < 6; i++) qv[i] = qs[tr * 6 + i][n];
#pragma unroll
        for (int j = 0; j < 6; j++) kv[j] = ks[tc * 6 + j][n];
#pragma unroll
        for (int i = 0; i < 6; i++)
#pragma unroll
            for (int j = 0; j < 6; j++) acc[i][j] += qv[i] * kv[j];
    }
    if (t < 48) {
        float sq = 0.f, sk = 0.f;
        for (int n = 0; n < 96; n++) {
            sq += qs[t][n] * qs[t][n];
            sk += ks[t][n] * ks[t][n];
        }
        atomicAdd(&qn[head * CPH + t], sq);
        atomicAdd(&kn[head * CPH + t], sk);
    }
    float* Sh = S + head * CPH * CPH;
#pragma unroll
    for (int i = 0; i < 6; i++)
#pragma unroll
        for (int j = 0; j < 6; j++)
            atomicAdd(&Sh[(tr * 6 + i) * CPH + tc * 6 + j], acc[i][j]);
}

// ---------------- K4: normalize + 4x nested top-k softmax, combined weights --
__global__ __launch_bounds__(256) void k_softmax(
    const float* __restrict__ S, const float* __restrict__ qn,
    const float* __restrict__ kn, const float* __restrict__ temp,
    const float* __restrict__ a1, const float* __restrict__ a2,
    const float* __restrict__ a3, const float* __restrict__ a4,
    float* __restrict__ Wc) {
    __shared__ float rowbuf[4][64];
    int lane = threadIdx.x & 63;
    int w = threadIdx.x >> 6;
    int row = blockIdx.x * 4 + w;        // 0..383
    int h = row / CPH, c = row % CPH;
    float a = -INFINITY;
    if (lane < CPH) {
        float s = S[(h * CPH + c) * CPH + lane];
        float nq = fmaxf(sqrtf(fmaxf(qn[h * CPH + c], 0.f)), 1e-12f);
        float nk = fmaxf(sqrtf(fmaxf(kn[h * CPH + lane], 0.f)), 1e-12f);
        a = s / (nq * nk) * temp[h];
    }
    rowbuf[w][lane] = a;
    __syncthreads();
    int rank = 0;
    float m = -INFINITY;
    for (int j = 0; j < CPH; j++) {
        float vj = rowbuf[w][j];
        m = fmaxf(m, vj);
        rank += (vj > a || (vj == a && j < lane)) ? 1 : 0;
    }
    float e = (lane < CPH) ? expf(a - m) : 0.f;
    float4 p;
    p.x = (rank < 24) ? e : 0.f;
    p.y = (rank < 32) ? e : 0.f;
    p.z = (rank < 36) ? e : 0.f;
    p.w = (rank < 38) ? e : 0.f;
#pragma unroll
    for (int off = 32; off > 0; off >>= 1) {
        p.x += __shfl_xor(p.x, off);
        p.y += __shfl_xor(p.y, off);
        p.z += __shfl_xor(p.z, off);
        p.w += __shfl_xor(p.w, off);
    }
    if (lane < CPH) {
        float wv = 0.f;
        if (rank < 24) wv += a1[0] / p.x;
        if (rank < 32) wv += a2[0] / p.y;
        if (rank < 36) wv += a3[0] / p.z;
        if (rank < 38) wv += a4[0] / p.w;
        Wc[(h * CPH + c) * CPH + lane] = e * wv;
    }
}

// ---------------- K5: out96 = gelu( Wc @ v ) ---------------------------------
// grid (18, 8 heads); thread: 2 pixels x 48 channels
__global__ __launch_bounds__(256) void k_av_gelu(
    const float* __restrict__ qkv, const float* __restrict__ Wc,
    float* __restrict__ out96) {
    __shared__ float Wt[48][48];   // [d][c]
    int tid = threadIdx.x;
    int h = blockIdx.y;
    int n = blockIdx.x * 512 + tid * 2;
#pragma unroll
    for (int it = 0; it < 9; it++) {
        int li = tid + 256 * it;
        if (li < 2304) {
            int dd = li / 48, cc = li - dd * 48;
            Wt[dd][cc] = Wc[(h * CPH + cc) * CPH + dd];
        }
    }
    __syncthreads();
    float2 acc[48];
#pragma unroll
    for (int c = 0; c < 48; c++) acc[c] = make_float2(0.f, 0.f);
    const float* vb = qkv + (size_t)(2 * D + h * CPH) * NP + n;
    for (int d = 0; d < 48; d++) {
        float2 vv = *(const float2*)&vb[(size_t)d * NP];
#pragma unroll
        for (int c4 = 0; c4 < 12; c4++) {
            float4 wv = *(const float4*)&Wt[d][c4 * 4];
            acc[c4 * 4 + 0].x += wv.x * vv.x; acc[c4 * 4 + 0].y += wv.x * vv.y;
            acc[c4 * 4 + 1].x += wv.y * vv.x; acc[c4 * 4 + 1].y += wv.y * vv.y;
            acc[c4 * 4 + 2].x += wv.z * vv.x; acc[c4 * 4 + 2].y += wv.z * vv.y;
            acc[c4 * 4 + 3].x += wv.w * vv.x; acc[c4 * 4 + 3].y += wv.w * vv.y;
        }
    }
#pragma unroll
    for (int c = 0; c < 48; c++) {
        float2 g = make_float2(gelu_exact(acc[c].x), gelu_exact(acc[c].y));
        *(float2*)&out96[(size_t)(h * CPH + c) * NP + n] = g;
    }
}

// ---------------- K6: proj 1x1 at 96x96 + nearest 2x upsample ----------------
// tile: 64 och x 64 px; thread: 4 och x 4 px
__global__ __launch_bounds__(256) void k_proj_up(
    const float* __restrict__ out96, const float* __restrict__ wp,
    const float* __restrict__ bp, float* __restrict__ out) {
    __shared__ float Xs[32][64];
    __shared__ float Ws[32][68];
    int tid = threadIdx.x;
    int tx = tid & 15, ty = tid >> 4;
    int o0 = blockIdx.y * 64;
    int n0 = blockIdx.x * 64;
    float4 acc[4];
#pragma unroll
    for (int i = 0; i < 4; i++) acc[i] = make_float4(0.f, 0.f, 0.f, 0.f);
    for (int kc = 0; kc < D; kc += 32) {
        __syncthreads();
#pragma unroll
        for (int it = 0; it < 8; it++) {
            int li = tid + 256 * it;
            int col = li & 63, k = li >> 6;
            Xs[k][col] = out96[(size_t)(kc + k) * NP + n0 + col];
        }
#pragma unroll
        for (int it = 0; it < 8; it++) {
            int li = tid + 256 * it;
            int kk = li & 31, ol = li >> 5;
            Ws[kk][ol] = wp[(size_t)(o0 + ol) * D + kc + kk];
        }
        __syncthreads();
#pragma unroll
        for (int k = 0; k < 32; k++) {
            float4 xv = *(const float4*)&Xs[k][tx * 4];
            float4 wv = *(const float4*)&Ws[k][ty * 4];
            fma4(acc[0], wv.x, xv);
            fma4(acc[1], wv.y, xv);
            fma4(acc[2], wv.z, xv);
            fma4(acc[3], wv.w, xv);
        }
    }
#pragma unroll
    for (int i = 0; i < 4; i++) {
        int o = o0 + ty * 4 + i;
        float bias = bp[o];
        float vals[4] = {acc[i].x + bias, acc[i].y + bias, acc[i].z + bias, acc[i].w + bias};
#pragma unroll
        for (int j = 0; j < 4; j++) {
            int n = n0 + tx * 4 + j;
            int yy = n / WP, xx = n - yy * WP;
            size_t base = (size_t)o * NF + (size_t)(2 * yy) * WFULL + 2 * xx;
            float2 vv = make_float2(vals[j], vals[j]);
            *(float2*)&out[base] = vv;
            *(float2*)&out[base + WFULL] = vv;
        }
    }
}

extern "C" void kernel_launch(void* const* d_in, const int* in_sizes, int n_in,
                              void* d_out, int out_size, void* d_ws, size_t ws_size,
                              hipStream_t stream) {
    (void)in_sizes; (void)n_in; (void)out_size; (void)ws_size;
    const float* x    = (const float*)d_in[0];
    const float* wq   = (const float*)d_in[1];
    const float* bq   = (const float*)d_in[2];
    const float* wd   = (const float*)d_in[3];
    const float* bd   = (const float*)d_in[4];
    const float* wp   = (const float*)d_in[5];
    const float* bp   = (const float*)d_in[6];
    const float* temp = (const float*)d_in[7];
    const float* a1   = (const float*)d_in[8];
    const float* a2   = (const float*)d_in[9];
    const float* a3   = (const float*)d_in[10];
    const float* a4   = (const float*)d_in[11];
    float* out = (float*)d_out;
    float* ws  = (float*)d_ws;

    float* pooled = ws;                       // 10,616,832 floats (42.5 MB)
    float* S      = ws + 10616832;            // 18,432
    float* qn     = S + 18432;                // 384
    float* kn     = qn + 384;                 // 384
    float* Wc     = kn + 384;                 // 18,432
    float* out96  = pooled;                   // reuse (pooled dead after K2)
    float* qkvdw  = out;                      // stage q,k,v after dw conv in d_out

    hipLaunchKernelGGL(k_zero,     dim3(75),          dim3(256), 0, stream, S, 19200);
    hipLaunchKernelGGL(k_qkv_pool, dim3(3, 96, 9),    dim3(256), 0, stream, x, wq, bq, pooled);
    hipLaunchKernelGGL(k_dwconv,   dim3(41472),       dim3(256), 0, stream, pooled, wd, bd, qkvdw);
    hipLaunchKernelGGL(k_attn,     dim3(96, 8),       dim3(64),  0, stream, qkvdw, S, qn, kn);
    hipLaunchKernelGGL(k_softmax,  dim3(96),          dim3(256), 0, stream, S, qn, kn, temp, a1, a2, a3, a4, Wc);
    hipLaunchKernelGGL(k_av_gelu,  dim3(18, 8),       dim3(256), 0, stream, qkvdw, Wc, out96);
    hipLaunchKernelGGL(k_proj_up,  dim3(144, 6),      dim3(256), 0, stream, out96, wp, bp, out);
}

// Round 3
// 363.897 us; speedup vs baseline: 1.9155x; 1.9155x over previous
//
#include <hip/hip_runtime.h>
#include <hip/hip_bf16.h>
#include <math.h>

#define NH    8
#define CPH   48
#define D     384
#define QC    1152
#define HF    192
#define WFULL 192
#define HP    96
#define WP    96
#define NP    9216    // 96*96
#define NF    36864   // 192*192

typedef __attribute__((ext_vector_type(8))) short short8;
typedef __attribute__((ext_vector_type(4))) float f32x4;

__device__ __forceinline__ void fma4(float4& a, float s, const float4& v) {
    a.x += s * v.x; a.y += s * v.y; a.z += s * v.z; a.w += s * v.w;
}
__device__ __forceinline__ float gelu_exact(float v) {
    return 0.5f * v * (1.f + erff(v * 0.70710678118654752440f));
}
__device__ __forceinline__ ushort f2bf(float v) {
    __hip_bfloat16 h = __float2bfloat16(v);
    return *reinterpret_cast<ushort*>(&h);
}
__device__ __forceinline__ float bf2f(ushort u) {
    __hip_bfloat16 h = *reinterpret_cast<__hip_bfloat16*>(&u);
    return __bfloat162float(h);
}

__global__ void k_zero(float* p, int n) {
    int i = blockIdx.x * 256 + threadIdx.x;
    if (i < n) p[i] = 0.f;
}

// ---------------- P1: split w into bf16 hi/lo --------------------------------
__global__ __launch_bounds__(256) void k_prep_w(
    const float* __restrict__ w, ushort* __restrict__ wh, ushort* __restrict__ wl, int n) {
    int i = blockIdx.x * 256 + threadIdx.x;
    if (i < n) {
        float v = w[i];
        ushort h = f2bf(v);
        wh[i] = h;
        wl[i] = f2bf(v - bf2f(h));
    }
}

// ---------------- P2: split+transpose x: [c][pix] fp32 -> [n'][c] bf16 hi/lo --
// n' = (py*96+px)*4 + (y&1)*2 + (x&1)   (pool-quad-contiguous pixel order)
__global__ __launch_bounds__(256) void k_prep_x(
    const float* __restrict__ x, ushort* __restrict__ xh, ushort* __restrict__ xl) {
    __shared__ float t[64][65];
    int tid = threadIdx.x;
    int c0 = blockIdx.y * 64;
    int p0 = blockIdx.x * 64;          // 64 pixels, always within one full-res row
#pragma unroll
    for (int it = 0; it < 16; it++) {
        int li = tid + 256 * it;
        int c = li >> 6, p = li & 63;
        t[c][p] = x[(size_t)(c0 + c) * NF + p0 + p];
    }
    __syncthreads();
    int y = p0 / WFULL;
#pragma unroll
    for (int it = 0; it < 8; it++) {
        int li = tid + 256 * it;
        int p = li >> 5, cc = (li & 31) * 2;
        int pg = p0 + p;
        int xx = pg - y * WFULL;
        int np = ((y >> 1) * WP + (xx >> 1)) * 4 + (y & 1) * 2 + (xx & 1);
        float v0 = t[cc][p], v1 = t[cc + 1][p];
        ushort h0 = f2bf(v0), h1 = f2bf(v1);
        ushort l0 = f2bf(v0 - bf2f(h0)), l1 = f2bf(v1 - bf2f(h1));
        ushort2 hh; hh.x = h0; hh.y = h1;
        ushort2 ll; ll.x = l0; ll.y = l1;
        *(ushort2*)&xh[(size_t)np * D + c0 + cc] = hh;
        *(ushort2*)&xl[(size_t)np * D + c0 + cc] = ll;
    }
}

// ---------------- K1: qkv 1x1 conv as bf16x3 MFMA GEMM + fused 2x2 maxpool ---
// C[n', o] = sum_k x'[n',k] w[o,k];  M=36864(n'), N=1152(o), K=384
// 128x128 tile, BK=32, 4 waves (2x2 of 64x64), 2-bit XOR-swizzled LDS,
// global_load_lds staging, XCD-aware block remap (9 n-tiles share A panel).
__global__ __launch_bounds__(256) void k_qkv_mfma(
    const ushort* __restrict__ xh, const ushort* __restrict__ xl,
    const ushort* __restrict__ wh, const ushort* __restrict__ wl,
    const float* __restrict__ bq, float* __restrict__ pooled) {
    __shared__ ushort lds[4][4096];    // Ah, Al, Bh, Bl : 128 rows x 32 bf16 (8KB each)
    const int tid = threadIdx.x;
    const int lane = tid & 63, wid = tid >> 6;
    const int wm = wid >> 1, wn = wid & 1;

    // XCD-aware remap: dispatch d -> same-XCD chunk of 36 m-tiles x 9 n-tiles
    const int d   = blockIdx.x;        // 0..2591, HW XCD = d % 8
    const int xcd = d & 7;
    const int idx = d >> 3;            // 0..323
    const int by  = xcd * 36 + idx / 9;
    const int bx  = idx % 9;
    const int n0 = bx * 128;           // out-channel tile
    const int m0 = by * 128;           // pixel tile

    const ushort* srcs[4];
    srcs[0] = xh + (size_t)m0 * D;
    srcs[1] = xl + (size_t)m0 * D;
    srcs[2] = wh + (size_t)n0 * D;
    srcs[3] = wl + (size_t)n0 * D;

    f32x4 acc[4][4];
#pragma unroll
    for (int i = 0; i < 4; i++)
#pragma unroll
        for (int j = 0; j < 4; j++) acc[i][j] = (f32x4){0.f, 0.f, 0.f, 0.f};

    // fragment ds_read byte offsets (within one 8KB tile), 2-bit XOR swizzle:
    // chunk' = chunk ^ ((row>>1)&3); row stride 64B
    int a_off[4], b_off[4];
#pragma unroll
    for (int f = 0; f < 4; f++) {
        int ra = wm * 64 + f * 16 + (lane & 15);
        a_off[f] = ra * 64 + ((((lane >> 4) ^ ((ra >> 1) & 3)) & 3) << 4);
        int rb = wn * 64 + f * 16 + (lane & 15);
        b_off[f] = rb * 64 + ((((lane >> 4) ^ ((rb >> 1) & 3)) & 3) << 4);
    }

    for (int ks = 0; ks < 12; ks++) {
        const int kk = ks * 32;
        __syncthreads();
        // stage 32KB: 4 waves x 8 issues x 64 lanes x 16B; linear LDS dest,
        // inverse-swizzled global source (both-sides rule, 2-bit chunk XOR)
#pragma unroll
        for (int i = 0; i < 8; i++) {
            const int mat = i >> 1;
            const int cm  = ((i & 1) << 2) | wid;        // 1KB chunk within tile
            const int row = cm * 16 + (lane >> 2);
            const int scol = (((lane & 3) ^ ((row >> 1) & 3)) & 3) << 4;  // bytes, <64
            const ushort* src = srcs[mat] + (size_t)row * D + kk + (scol >> 1);
            __builtin_amdgcn_global_load_lds(
                (const __attribute__((address_space(1))) void*)src,
                (__attribute__((address_space(3))) void*)&lds[mat][cm * 512],
                16, 0, 0);
        }
        __syncthreads();   // compiler drains vmcnt before barrier

        short8 A[2][4], B[2][4];
#pragma unroll
        for (int f = 0; f < 4; f++) {
            A[0][f] = *(const short8*)((const char*)&lds[0][0] + a_off[f]);
            A[1][f] = *(const short8*)((const char*)&lds[1][0] + a_off[f]);
            B[0][f] = *(const short8*)((const char*)&lds[2][0] + b_off[f]);
            B[1][f] = *(const short8*)((const char*)&lds[3][0] + b_off[f]);
        }
#pragma unroll
        for (int fm = 0; fm < 4; fm++)
#pragma unroll
            for (int fn = 0; fn < 4; fn++) {
                acc[fm][fn] = __builtin_amdgcn_mfma_f32_16x16x32_bf16(A[0][fm], B[0][fn], acc[fm][fn], 0, 0, 0);
                acc[fm][fn] = __builtin_amdgcn_mfma_f32_16x16x32_bf16(A[0][fm], B[1][fn], acc[fm][fn], 0, 0, 0);
                acc[fm][fn] = __builtin_amdgcn_mfma_f32_16x16x32_bf16(A[1][fm], B[0][fn], acc[fm][fn], 0, 0, 0);
            }
    }

    // epilogue: 4 C-regs of each fragment = one pool quad (n' is quad-contiguous)
    const int p_base = by * 32 + wm * 16 + (lane >> 4);
#pragma unroll
    for (int fn = 0; fn < 4; fn++) {
        const int o = n0 + wn * 64 + fn * 16 + (lane & 15);
        const float b = bq[o];
#pragma unroll
        for (int fm = 0; fm < 4; fm++) {
            f32x4 v = acc[fm][fn];
            float mx = fmaxf(fmaxf(v.x, v.y), fmaxf(v.z, v.w)) + b;
            pooled[(size_t)o * NP + p_base + fm * 4] = mx;
        }
    }
}

// ---------------- K2: depthwise 3x3 conv, SAME padding -----------------------
__global__ __launch_bounds__(256) void k_dwconv(
    const float* __restrict__ pooled, const float* __restrict__ wd,
    const float* __restrict__ bd, float* __restrict__ out) {
    int gid = blockIdx.x * 256 + threadIdx.x;
    int ch = gid / NP;
    int n  = gid - ch * NP;
    int y  = n / WP;
    int x0 = n - y * WP;
    const float* src = pooled + (size_t)ch * NP;
    const float* w = wd + ch * 9;
    float s = bd[ch];
#pragma unroll
    for (int dy = 0; dy < 3; dy++) {
        int yy = y + dy - 1;
        if (yy < 0 || yy >= HP) continue;
#pragma unroll
        for (int dx = 0; dx < 3; dx++) {
            int xx = x0 + dx - 1;
            if (xx < 0 || xx >= WP) continue;
            s += src[yy * WP + xx] * w[dy * 3 + dx];
        }
    }
    out[gid] = s;
}

// ---------------- K3: attn partials S = q.k^T, plus sq-norms -----------------
__global__ __launch_bounds__(64) void k_attn(
    const float* __restrict__ qkv, float* __restrict__ S,
    float* __restrict__ qn, float* __restrict__ kn) {
    __shared__ float qs[48][97], ks[48][97];
    int t = threadIdx.x;
    int head = blockIdx.y;
    int n0 = blockIdx.x * 96;
    const float* qb = qkv + (size_t)(head * CPH) * NP + n0;
    const float* kb = qkv + (size_t)(D + head * CPH) * NP + n0;
    for (int it = 0; it < 72; it++) {
        int li = t + 64 * it;
        int col = li % 96, row = li / 96;
        qs[row][col] = qb[(size_t)row * NP + col];
        ks[row][col] = kb[(size_t)row * NP + col];
    }
    __syncthreads();
    int tr = t >> 3, tc = t & 7;
    float acc[6][6] = {};
    for (int n = 0; n < 96; n++) {
        float qv[6], kv[6];
#pragma unroll
        for (int i = 0; i < 6; i++) qv[i] = qs[tr * 6 + i][n];
#pragma unroll
        for (int j = 0; j < 6; j++) kv[j] = ks[tc * 6 + j][n];
#pragma unroll
        for (int i = 0; i < 6; i++)
#pragma unroll
            for (int j = 0; j < 6; j++) acc[i][j] += qv[i] * kv[j];
    }
    if (t < 48) {
        float sq = 0.f, sk = 0.f;
        for (int n = 0; n < 96; n++) {
            sq += qs[t][n] * qs[t][n];
            sk += ks[t][n] * ks[t][n];
        }
        atomicAdd(&qn[head * CPH + t], sq);
        atomicAdd(&kn[head * CPH + t], sk);
    }
    float* Sh = S + head * CPH * CPH;
#pragma unroll
    for (int i = 0; i < 6; i++)
#pragma unroll
        for (int j = 0; j < 6; j++)
            atomicAdd(&Sh[(tr * 6 + i) * CPH + tc * 6 + j], acc[i][j]);
}

// ---------------- K4: normalize + 4x nested top-k softmax --------------------
__global__ __launch_bounds__(256) void k_softmax(
    const float* __restrict__ S, const float* __restrict__ qn,
    const float* __restrict__ kn, const float* __restrict__ temp,
    const float* __restrict__ a1, const float* __restrict__ a2,
    const float* __restrict__ a3, const float* __restrict__ a4,
    float* __restrict__ Wc) {
    __shared__ float rowbuf[4][64];
    int lane = threadIdx.x & 63;
    int w = threadIdx.x >> 6;
    int row = blockIdx.x * 4 + w;
    int h = row / CPH, c = row % CPH;
    float a = -INFINITY;
    if (lane < CPH) {
        float s = S[(h * CPH + c) * CPH + lane];
        float nq = fmaxf(sqrtf(fmaxf(qn[h * CPH + c], 0.f)), 1e-12f);
        float nk = fmaxf(sqrtf(fmaxf(kn[h * CPH + lane], 0.f)), 1e-12f);
        a = s / (nq * nk) * temp[h];
    }
    rowbuf[w][lane] = a;
    __syncthreads();
    int rank = 0;
    float m = -INFINITY;
    for (int j = 0; j < CPH; j++) {
        float vj = rowbuf[w][j];
        m = fmaxf(m, vj);
        rank += (vj > a || (vj == a && j < lane)) ? 1 : 0;
    }
    float e = (lane < CPH) ? expf(a - m) : 0.f;
    float4 p;
    p.x = (rank < 24) ? e : 0.f;
    p.y = (rank < 32) ? e : 0.f;
    p.z = (rank < 36) ? e : 0.f;
    p.w = (rank < 38) ? e : 0.f;
#pragma unroll
    for (int off = 32; off > 0; off >>= 1) {
        p.x += __shfl_xor(p.x, off);
        p.y += __shfl_xor(p.y, off);
        p.z += __shfl_xor(p.z, off);
        p.w += __shfl_xor(p.w, off);
    }
    if (lane < CPH) {
        float wv = 0.f;
        if (rank < 24) wv += a1[0] / p.x;
        if (rank < 32) wv += a2[0] / p.y;
        if (rank < 36) wv += a3[0] / p.z;
        if (rank < 38) wv += a4[0] / p.w;
        Wc[(h * CPH + c) * CPH + lane] = e * wv;
    }
}

// ---------------- K5: out96 = gelu( Wc @ v ) ---------------------------------
__global__ __launch_bounds__(256) void k_av_gelu(
    const float* __restrict__ qkv, const float* __restrict__ Wc,
    float* __restrict__ out96) {
    __shared__ float Wt[48][48];
    int tid = threadIdx.x;
    int h = blockIdx.y;
    int n = blockIdx.x * 512 + tid * 2;
#pragma unroll
    for (int it = 0; it < 9; it++) {
        int li = tid + 256 * it;
        if (li < 2304) {
            int dd = li / 48, cc = li - dd * 48;
            Wt[dd][cc] = Wc[(h * CPH + cc) * CPH + dd];
        }
    }
    __syncthreads();
    float2 acc[48];
#pragma unroll
    for (int c = 0; c < 48; c++) acc[c] = make_float2(0.f, 0.f);
    const float* vb = qkv + (size_t)(2 * D + h * CPH) * NP + n;
    for (int d = 0; d < 48; d++) {
        float2 vv = *(const float2*)&vb[(size_t)d * NP];
#pragma unroll
        for (int c4 = 0; c4 < 12; c4++) {
            float4 wv = *(const float4*)&Wt[d][c4 * 4];
            acc[c4 * 4 + 0].x += wv.x * vv.x; acc[c4 * 4 + 0].y += wv.x * vv.y;
            acc[c4 * 4 + 1].x += wv.y * vv.x; acc[c4 * 4 + 1].y += wv.y * vv.y;
            acc[c4 * 4 + 2].x += wv.z * vv.x; acc[c4 * 4 + 2].y += wv.z * vv.y;
            acc[c4 * 4 + 3].x += wv.w * vv.x; acc[c4 * 4 + 3].y += wv.w * vv.y;
        }
    }
#pragma unroll
    for (int c = 0; c < 48; c++) {
        float2 g = make_float2(gelu_exact(acc[c].x), gelu_exact(acc[c].y));
        *(float2*)&out96[(size_t)(h * CPH + c) * NP + n] = g;
    }
}

// ---------------- K6: proj 1x1 at 96x96 + nearest 2x upsample ----------------
__global__ __launch_bounds__(256) void k_proj_up(
    const float* __restrict__ out96, const float* __restrict__ wp,
    const float* __restrict__ bp, float* __restrict__ out) {
    __shared__ float Xs[32][64];
    __shared__ float Ws[32][68];
    int tid = threadIdx.x;
    int tx = tid & 15, ty = tid >> 4;
    int o0 = blockIdx.y * 64;
    int n0 = blockIdx.x * 64;
    float4 acc[4];
#pragma unroll
    for (int i = 0; i < 4; i++) acc[i] = make_float4(0.f, 0.f, 0.f, 0.f);
    for (int kc = 0; kc < D; kc += 32) {
        __syncthreads();
#pragma unroll
        for (int it = 0; it < 8; it++) {
            int li = tid + 256 * it;
            int col = li & 63, k = li >> 6;
            Xs[k][col] = out96[(size_t)(kc + k) * NP + n0 + col];
        }
#pragma unroll
        for (int it = 0; it < 8; it++) {
            int li = tid + 256 * it;
            int kk = li & 31, ol = li >> 5;
            Ws[kk][ol] = wp[(size_t)(o0 + ol) * D + kc + kk];
        }
        __syncthreads();
#pragma unroll
        for (int k = 0; k < 32; k++) {
            float4 xv = *(const float4*)&Xs[k][tx * 4];
            float4 wv = *(const float4*)&Ws[k][ty * 4];
            fma4(acc[0], wv.x, xv);
            fma4(acc[1], wv.y, xv);
            fma4(acc[2], wv.z, xv);
            fma4(acc[3], wv.w, xv);
        }
    }
#pragma unroll
    for (int i = 0; i < 4; i++) {
        int o = o0 + ty * 4 + i;
        float bias = bp[o];
        float vals[4] = {acc[i].x + bias, acc[i].y + bias, acc[i].z + bias, acc[i].w + bias};
#pragma unroll
        for (int j = 0; j < 4; j++) {
            int n = n0 + tx * 4 + j;
            int yy = n / WP, xx = n - yy * WP;
            size_t base = (size_t)o * NF + (size_t)(2 * yy) * WFULL + 2 * xx;
            float2 vv = make_float2(vals[j], vals[j]);
            *(float2*)&out[base] = vv;
            *(float2*)&out[base + WFULL] = vv;
        }
    }
}

extern "C" void kernel_launch(void* const* d_in, const int* in_sizes, int n_in,
                              void* d_out, int out_size, void* d_ws, size_t ws_size,
                              hipStream_t stream) {
    (void)in_sizes; (void)n_in; (void)out_size; (void)ws_size;
    const float* x    = (const float*)d_in[0];
    const float* wq   = (const float*)d_in[1];
    const float* bq   = (const float*)d_in[2];
    const float* wd   = (const float*)d_in[3];
    const float* bd   = (const float*)d_in[4];
    const float* wp   = (const float*)d_in[5];
    const float* bp   = (const float*)d_in[6];
    const float* temp = (const float*)d_in[7];
    const float* a1   = (const float*)d_in[8];
    const float* a2   = (const float*)d_in[9];
    const float* a3   = (const float*)d_in[10];
    const float* a4   = (const float*)d_in[11];
    float* out = (float*)d_out;
    float* ws  = (float*)d_ws;

    float* pooled = ws;                       // 10,616,832 floats
    float* S      = ws + 10616832;            // 18,432
    float* qn     = S + 18432;                // 384
    float* kn     = qn + 384;                 // 384
    float* Wc     = kn + 384;                 // 18,432
    ushort* wh    = (ushort*)(Wc + 18432);    // 442,368 bf16
    ushort* wl    = wh + 442368;              // 442,368 bf16
    float* out96  = pooled;                   // reuse (pooled dead after K2)
    float* qkvdw  = out;                      // q,k,v after dw conv staged in d_out

    // x split (bf16 hi/lo) staged in d_out; dead before dwconv overwrites it
    ushort* xh = (ushort*)d_out;              // 14,155,776 bf16
    ushort* xl = xh + 14155776;               // 14,155,776 bf16

    hipLaunchKernelGGL(k_zero,     dim3(75),        dim3(256), 0, stream, S, 19200);
    hipLaunchKernelGGL(k_prep_w,   dim3(1728),      dim3(256), 0, stream, wq, wh, wl, QC * D);
    hipLaunchKernelGGL(k_prep_x,   dim3(576, 6),    dim3(256), 0, stream, x, xh, xl);
    hipLaunchKernelGGL(k_qkv_mfma, dim3(2592),      dim3(256), 0, stream, xh, xl, wh, wl, bq, pooled);
    hipLaunchKernelGGL(k_dwconv,   dim3(41472),     dim3(256), 0, stream, pooled, wd, bd, qkvdw);
    hipLaunchKernelGGL(k_attn,     dim3(96, 8),     dim3(64),  0, stream, qkvdw, S, qn, kn);
    hipLaunchKernelGGL(k_softmax,  dim3(96),        dim3(256), 0, stream, S, qn, kn, temp, a1, a2, a3, a4, Wc);
    hipLaunchKernelGGL(k_av_gelu,  dim3(18, 8),     dim3(256), 0, stream, qkvdw, Wc, out96);
    hipLaunchKernelGGL(k_proj_up,  dim3(144, 6),    dim3(256), 0, stream, out96, wp, bp, out);
}